// Round 11
// baseline (1934.194 us; speedup 1.0000x reference)
//
#include <hip/hip_runtime.h>
#include <hip/hip_bf16.h>

// Problem constants
#define MROW 8192   // BATCH
#define DIMK 4096   // DIM (= K of both GEMMs)
#define NCOL 4096   // N_HEADS*HIDDEN = DIM
#define HID  256
#define NH   16
#define SEQL 4096

// Flat GEMM: NO LDS, NO barriers. 8 waves (2M x 4N), each wave owns a 64x64
// output tile; MFMA fragments loaded directly global->VGPR (L1/L2 cached),
// register double-buffer depth 2 over K-chunks of 32.
#define NKC (DIMK / 32)        // 128 K-chunks

typedef __attribute__((ext_vector_type(8))) short short8;
typedef __attribute__((ext_vector_type(4))) float f32x4;

__device__ inline ushort f2bf(float f) {
  unsigned u = __float_as_uint(f);
  u += 0x7FFF + ((u >> 16) & 1);   // RNE
  return (ushort)(u >> 16);
}

// fp32 -> bf16, 8 elements/thread, grid-stride
__global__ void cvt_f32_bf16(const float* __restrict__ s, ushort* __restrict__ d, long n8) {
  long stride = (long)gridDim.x * blockDim.x;
  for (long i = (long)blockIdx.x * blockDim.x + threadIdx.x; i < n8; i += stride) {
    const float4* s4 = (const float4*)(s + i * 8);
    float4 a = s4[0], b = s4[1];
    ushort r[8] = {f2bf(a.x), f2bf(a.y), f2bf(a.z), f2bf(a.w),
                   f2bf(b.x), f2bf(b.y), f2bf(b.z), f2bf(b.w)};
    *(uint4*)(d + i * 8) = *(const uint4*)r;
  }
}

// per-output-column coefficients for the GEMM1 epilogue
__global__ void coef_kernel(const float* __restrict__ mix_w, const float* __restrict__ mix_b,
                            const float* __restrict__ decay_value, const float* __restrict__ proj_b,
                            const int* __restrict__ index_p,
                            float* __restrict__ wv, float* __restrict__ cc, float* __restrict__ pb2) {
  int n = blockIdx.x * blockDim.x + threadIdx.x;   // 0..4095
  if (n >= NCOL) return;
  int h = n >> 8;
  int idx = *index_p;
  float w  = mix_w[h * SEQL + idx];
  float bb = mix_b[h * SEQL + idx];
  float dv = fminf(fmaxf(decay_value[h], 0.9f), 1.0f);
  float decay = powf(dv, 0.125f);                  // 1/DECAY_CONSTANT (=8)
  float coef = (h < NH / 2) ? w * decay : decay;
  wv[n]  = w;
  cc[n]  = coef;
  pb2[n] = w * proj_b[n] + bb;
}

// C = A(MxK)*B^T(NxK), bf16, 16x16x32 MFMA, flat (no LDS). Fragment loads go
// straight to VGPRs; L1 serves the intra-CU reuse (4 wc-waves share A lines,
// 2 wr-waves share B lines), L2 the inter-block reuse (XCD swizzle).
// Register dbuf: load chunk kc+1 while MFMA-ing chunk kc; the compiler emits
// the counted vmcnt from the register dependences.
// EPI==1: mix epilogue -> bf16 hidden.  EPI==0: +out_b -> f32 out.
template <int EPI>
__global__ __launch_bounds__(512, 2) void gemmflat(
    const ushort* __restrict__ A, const ushort* __restrict__ B,
    float* __restrict__ outf, ushort* __restrict__ outh,
    const float* __restrict__ cache, const float* __restrict__ wv,
    const float* __restrict__ cc, const float* __restrict__ pb2,
    const float* __restrict__ outb) {
  const int tid  = threadIdx.x;
  const int lane = tid & 63;
  const int wid  = tid >> 6;      // 0..7
  const int wr = wid >> 2;        // 0..1 (M): wave rows  wr*64..+63
  const int wc = wid & 3;         // 0..3 (N): wave cols  wc*64..+63
  const int r16 = lane & 15;
  const int cq  = lane >> 4;      // k-octet 0..3

  // XCD swizzle (grid 1024, 1024 % 8 == 0, bijective)
  const int bid = blockIdx.x;
  const int swz = (bid & 7) * 128 + (bid >> 3);
  const int bm = swz >> 4, bn = swz & 15;   // 64 x 16 tiles of 128x256
  const int m0 = bm * 128, n0 = bn * 256;

  // per-lane fragment base pointers (frag i adds i*16 rows; kc adds kc*32 elems)
  const ushort* Ag = A + (size_t)(m0 + wr * 64 + r16) * DIMK + cq * 8;
  const ushort* Bg = B + (size_t)(n0 + wc * 64 + r16) * DIMK + cq * 8;

  f32x4 acc[4][4] = {};
  short8 a0[4], b0[4], a1[4], b1[4];

#define LDF(da, db, kc) do {                                                   \
    const size_t ko_ = (size_t)(kc) * 32;                                      \
    _Pragma("unroll")                                                          \
    for (int i_ = 0; i_ < 4; ++i_)                                             \
      da[i_] = *(const short8*)(Ag + (size_t)i_ * 16 * DIMK + ko_);            \
    _Pragma("unroll")                                                          \
    for (int i_ = 0; i_ < 4; ++i_)                                             \
      db[i_] = *(const short8*)(Bg + (size_t)i_ * 16 * DIMK + ko_);            \
  } while (0)

#define FMA16(aa, bb) do {                                                     \
    __builtin_amdgcn_s_setprio(1);                                             \
    _Pragma("unroll")                                                          \
    for (int mi_ = 0; mi_ < 4; ++mi_)                                          \
      _Pragma("unroll")                                                        \
      for (int ni_ = 0; ni_ < 4; ++ni_)                                        \
        acc[mi_][ni_] = __builtin_amdgcn_mfma_f32_16x16x32_bf16(               \
            aa[mi_], bb[ni_], acc[mi_][ni_], 0, 0, 0);                         \
    __builtin_amdgcn_s_setprio(0);                                             \
  } while (0)

  LDF(a0, b0, 0);
  for (int kc = 0; kc < NKC; kc += 2) {
    LDF(a1, b1, kc + 1);
    FMA16(a0, b0);
    if (kc + 2 < NKC) LDF(a0, b0, kc + 2);
    FMA16(a1, b1);
  }

  // ---- epilogue. C/D 16x16 map: col = lane&15, row = (lane>>4)*4 + reg
  const int colb = n0 + wc * 64 + r16;
  const int rowb = m0 + wr * 64 + cq * 4;

  float wvv[4], ccv[4], pbv[4], obv[4];
#pragma unroll
  for (int ni = 0; ni < 4; ++ni) {
    int n = colb + ni * 16;
    if (EPI == 1) { wvv[ni] = wv[n]; ccv[ni] = cc[n]; pbv[ni] = pb2[n]; }
    else          { obv[ni] = outb[n]; }
  }

#pragma unroll
  for (int mi = 0; mi < 4; ++mi) {
#pragma unroll
    for (int ni = 0; ni < 4; ++ni) {
      f32x4 v = acc[mi][ni];
      int n = colb + ni * 16;
#pragma unroll
      for (int r = 0; r < 4; ++r) {
        int m = rowb + mi * 16 + r;
        if (EPI == 1) {
          int h = n >> 8, kq = n & 255;
          float val = wvv[ni] * v[r] + ccv[ni] * cache[((size_t)h * MROW + m) * HID + kq] + pbv[ni];
          outh[(size_t)m * NCOL + n] = f2bf(val);
        } else {
          outf[(size_t)m * NCOL + n] = v[r] + obv[ni];
        }
      }
    }
  }
#undef LDF
#undef FMA16
}

extern "C" void kernel_launch(void* const* d_in, const int* in_sizes, int n_in,
                              void* d_out, int out_size, void* d_ws, size_t ws_size,
                              hipStream_t stream) {
  const float* x      = (const float*)d_in[0];
  const float* proj_w = (const float*)d_in[1];
  const float* proj_b = (const float*)d_in[2];
  const float* mix_w  = (const float*)d_in[3];
  const float* mix_b  = (const float*)d_in[4];
  const float* decay  = (const float*)d_in[5];
  const float* cache  = (const float*)d_in[6];
  const float* out_w  = (const float*)d_in[7];
  const float* out_b  = (const float*)d_in[8];
  const int*   index  = (const int*)d_in[9];

  char* ws = (char*)d_ws;
  ushort* xb  = (ushort*)ws;                         // 64 MiB
  ushort* pwb = (ushort*)(ws + 67108864);            // 32 MiB
  ushort* owb = (ushort*)(ws + 100663296);           // 32 MiB
  ushort* hid = (ushort*)(ws + 134217728);           // 64 MiB
  float*  wv  = (float*)(ws + 201326592);
  float*  cc  = (float*)(ws + 201326592 + 16384);
  float*  pb2 = (float*)(ws + 201326592 + 32768);

  hipLaunchKernelGGL(cvt_f32_bf16, dim3(2048), dim3(256), 0, stream,
                     x, xb, (long)MROW * DIMK / 8);
  hipLaunchKernelGGL(cvt_f32_bf16, dim3(1024), dim3(256), 0, stream,
                     proj_w, pwb, (long)NCOL * DIMK / 8);
  hipLaunchKernelGGL(cvt_f32_bf16, dim3(1024), dim3(256), 0, stream,
                     out_w, owb, (long)NCOL * DIMK / 8);
  hipLaunchKernelGGL(coef_kernel, dim3(16), dim3(256), 0, stream,
                     mix_w, mix_b, decay, proj_b, index, wv, cc, pb2);

  const int grid = (MROW / 128) * (NCOL / 256);   // 1024 blocks

  // GEMM1: hidden = mix(x @ proj_w^T) -> bf16
  hipLaunchKernelGGL((gemmflat<1>), dim3(grid), dim3(512), 0, stream,
                     xb, pwb, nullptr, hid, cache, wv, cc, pb2, nullptr);
  // GEMM2: out = hidden @ out_w^T + out_b -> f32
  hipLaunchKernelGGL((gemmflat<0>), dim3(grid), dim3(512), 0, stream,
                     hid, owb, (float*)d_out, nullptr, nullptr, nullptr, nullptr, nullptr, out_b);
}

// Round 13
// 592.040 us; speedup vs baseline: 3.2670x; 3.2670x over previous
//
#include <hip/hip_runtime.h>
#include <hip/hip_bf16.h>

// Problem constants
#define MROW 8192   // BATCH
#define DIMK 4096   // DIM (= K of both GEMMs)
#define NCOL 4096   // N_HEADS*HIDDEN = DIM
#define HID  256
#define NH   16
#define SEQL 4096

// GEMM: 256x256 tile, BK=64 (two 32-k slices), 8 waves (2M x 4N, wave 128x64),
// dbuf 2 x 64KB. 4 phases per K-tile, K-SPLIT half-tiles (use-order is
// wave-uniform): ph0 ks0/mh0, ph1 ks0/mh1, ph2 ks1/mh0, ph3 ks1/mh1.
// Stage one half (2 gloads) per phase; vmcnt(4) at ph1/ph3 only — never drains.
#define BKT 64
#define NKT (DIMK / BKT)       // 64 K-tiles
#define BUFB 65536             // [A-k0|A-k1|B-k0|B-k1] x 16KB
#define LDS_TOTAL (2 * BUFB)   // 131072

typedef __attribute__((ext_vector_type(8))) short short8;
typedef __attribute__((ext_vector_type(4))) float f32x4;

#define LG0() do { asm volatile("s_waitcnt lgkmcnt(0)" ::: "memory"); \
                   __builtin_amdgcn_sched_barrier(0); } while (0)

__device__ inline ushort f2bf(float f) {
  unsigned u = __float_as_uint(f);
  u += 0x7FFF + ((u >> 16) & 1);   // RNE
  return (ushort)(u >> 16);
}

__device__ inline void gload16(const void* g, void* l) {
  __builtin_amdgcn_global_load_lds(
      (const __attribute__((address_space(1))) void*)g,
      (__attribute__((address_space(3))) void*)l, 16, 0, 0);
}

// fp32 -> bf16, 8 elements/thread, grid-stride
__global__ void cvt_f32_bf16(const float* __restrict__ s, ushort* __restrict__ d, long n8) {
  long stride = (long)gridDim.x * blockDim.x;
  for (long i = (long)blockIdx.x * blockDim.x + threadIdx.x; i < n8; i += stride) {
    const float4* s4 = (const float4*)(s + i * 8);
    float4 a = s4[0], b = s4[1];
    ushort r[8] = {f2bf(a.x), f2bf(a.y), f2bf(a.z), f2bf(a.w),
                   f2bf(b.x), f2bf(b.y), f2bf(b.z), f2bf(b.w)};
    *(uint4*)(d + i * 8) = *(const uint4*)r;
  }
}

// per-output-column coefficients for the GEMM1 epilogue
__global__ void coef_kernel(const float* __restrict__ mix_w, const float* __restrict__ mix_b,
                            const float* __restrict__ decay_value, const float* __restrict__ proj_b,
                            const int* __restrict__ index_p,
                            float* __restrict__ wv, float* __restrict__ cc, float* __restrict__ pb2) {
  int n = blockIdx.x * blockDim.x + threadIdx.x;   // 0..4095
  if (n >= NCOL) return;
  int h = n >> 8;
  int idx = *index_p;
  float w  = mix_w[h * SEQL + idx];
  float bb = mix_b[h * SEQL + idx];
  float dv = fminf(fmaxf(decay_value[h], 0.9f), 1.0f);
  float decay = powf(dv, 0.125f);                  // 1/DECAY_CONSTANT (=8)
  float coef = (h < NH / 2) ? w * decay : decay;
  wv[n]  = w;
  cc[n]  = coef;
  pb2[n] = w * proj_b[n] + bb;
}

// C = A(MxK)*B^T(NxK), bf16. Each k-slice half = 256 rows x 32 k (16KB), LDS
// rows of 64B (4 x 16B slots), swizzle slot' = slot ^ ((row>>1)&3) (R6 layout,
// measured 0 conflicts), inverse-applied on the global staging source.
// Ledger: stage(kt->kt+1): ph0 A-k0, ph1 B-k0, ph2 A-k1, ph3 B-k1.
//   vmcnt(4)@ph1-end  => A-k1,B-k1(kt) landed   (read ph2/ph3 of kt)     OK
//   vmcnt(4)@ph3-end  => A-k0,B-k0(kt+1) landed (read ph0/ph1 of kt+1)   OK
//   tail: vmcnt(0)@ph1-end of last tile (its k1 halves have no cover otherwise).
template <int EPI>
__global__ __launch_bounds__(512, 2) void gemmkp(
    const ushort* __restrict__ A, const ushort* __restrict__ B,
    float* __restrict__ outf, ushort* __restrict__ outh,
    const float* __restrict__ cache, const float* __restrict__ wv,
    const float* __restrict__ cc, const float* __restrict__ pb2,
    const float* __restrict__ outb) {
  extern __shared__ __align__(16) char smem[];

  const int tid  = threadIdx.x;
  const int lane = tid & 63;
  const int wid  = tid >> 6;      // 0..7
  const int wr = wid >> 2;        // 0..1 (M): rows wr*128..+127
  const int wc = wid & 3;         // 0..3 (N): cols wc*64..+63
  const int r16 = lane & 15;
  const int cq  = lane >> 4;      // 0..3

  // XCD swizzle (grid 512, bijective)
  const int bid = blockIdx.x;
  const int swz = (bid & 7) * 64 + (bid >> 3);
  const int bm = swz >> 4, bn = swz & 15;   // 32 x 16 tiles
  const int m0 = bm * 256, n0 = bn * 256;

  const ushort* Ag = A + (size_t)m0 * DIMK;
  const ushort* Bg = B + (size_t)n0 * DIMK;

  // read geometry: addr(half, row, cq) = halfbase + row*64 + ((cq^((row>>1)&3))<<4)
  // (row>>1)&3 == (r16>>1)&3 for all frag rows (bases are multiples of 16).
  const int sx    = (cq ^ ((r16 >> 1) & 3)) << 4;
  const int aBase = (wr * 128 + r16) * 64 + sx;          // + ks*16384 + mh*4096 + i*1024
  const int bBase = (wc * 64 + r16) * 64 + sx;           // + 32768 + ks*16384 + n*1024

  // stage addressing: linear LDS dest, inverse-swizzled global src (per k-slice)
  int ldst[2], sgo[2];
#pragma unroll
  for (int j = 0; j < 2; ++j) {
    int off = j * 8192 + tid * 16;                       // [0, 16KB) within a half
    int row = off >> 6;                                  // 0..255
    ldst[j] = off;
    sgo[j]  = row * DIMK + ((((off >> 4) & 3) ^ ((row >> 1) & 3)) << 3);
  }

  f32x4 acc[8][4] = {};
  short8 af[4], bf[4];

#define RD_B(ks) do { _Pragma("unroll") for (int n_ = 0; n_ < 4; ++n_)          \
    bf[n_] = *(const short8*)(cur + 32768 + (ks)*16384 + bBase + n_*1024); } while (0)
#define RD_A(ks, mh) do { _Pragma("unroll") for (int i_ = 0; i_ < 4; ++i_)      \
    af[i_] = *(const short8*)(cur + (ks)*16384 + aBase + (mh)*4096 + i_*1024); } while (0)
#define MM(mh) do {                                                             \
    __builtin_amdgcn_s_setprio(1);                                              \
    _Pragma("unroll") for (int i_ = 0; i_ < 4; ++i_)                            \
      _Pragma("unroll") for (int n_ = 0; n_ < 4; ++n_)                          \
        acc[(mh)*4+i_][n_] = __builtin_amdgcn_mfma_f32_16x16x32_bf16(           \
            af[i_], bf[n_], acc[(mh)*4+i_][n_], 0, 0, 0);                       \
    __builtin_amdgcn_s_setprio(0); } while (0)
#define STG_A(ks, t, buf) do { _Pragma("unroll") for (int j_ = 0; j_ < 2; ++j_) \
    gload16(Ag + (size_t)sgo[j_] + (size_t)(t)*BKT + (ks)*32,                   \
            (buf) + (ks)*16384 + ldst[j_]); } while (0)
#define STG_B(ks, t, buf) do { _Pragma("unroll") for (int j_ = 0; j_ < 2; ++j_) \
    gload16(Bg + (size_t)sgo[j_] + (size_t)(t)*BKT + (ks)*32,                   \
            (buf) + 32768 + (ks)*16384 + ldst[j_]); } while (0)

  // prologue: stage tile 0 fully into buf0 (8 gloads/thread)
  STG_A(0, 0, smem); STG_B(0, 0, smem); STG_A(1, 0, smem); STG_B(1, 0, smem);
  asm volatile("s_waitcnt vmcnt(0)" ::: "memory");
  __builtin_amdgcn_s_barrier();

  for (int kt = 0; kt < NKT; ++kt) {
    const char* cur = smem + (kt & 1) * BUFB;
    char*       nxt = smem + ((kt + 1) & 1) * BUFB;
    const bool  st   = (kt + 1) < NKT;
    const bool  last = (kt == NKT - 1);

    // ---- phase 0: ks0/mh0; stage A-k0(kt+1)
    RD_B(0); RD_A(0, 0);
    if (st) STG_A(0, kt + 1, nxt);
    __builtin_amdgcn_s_barrier(); LG0();
    MM(0);
    __builtin_amdgcn_s_barrier();

    // ---- phase 1: ks0/mh1; stage B-k0(kt+1); vmcnt(4) -> k1(kt) landed
    RD_A(0, 1);
    if (st) STG_B(0, kt + 1, nxt);
    __builtin_amdgcn_s_barrier(); LG0();
    MM(1);
    if (last) asm volatile("s_waitcnt vmcnt(0)" ::: "memory");
    else      asm volatile("s_waitcnt vmcnt(4)" ::: "memory");
    __builtin_amdgcn_s_barrier();

    // ---- phase 2: ks1/mh0; stage A-k1(kt+1)
    RD_B(1); RD_A(1, 0);
    if (st) STG_A(1, kt + 1, nxt);
    __builtin_amdgcn_s_barrier(); LG0();
    MM(0);
    __builtin_amdgcn_s_barrier();

    // ---- phase 3: ks1/mh1; stage B-k1(kt+1); vmcnt(4) -> k0(kt+1) landed
    RD_A(1, 1);
    if (st) STG_B(1, kt + 1, nxt);
    __builtin_amdgcn_s_barrier(); LG0();
    MM(1);
    if (!last) asm volatile("s_waitcnt vmcnt(4)" ::: "memory");
    __builtin_amdgcn_s_barrier();
  }
#undef RD_A
#undef RD_B
#undef MM
#undef STG_A
#undef STG_B

  // ---- epilogue. C/D 16x16 map: col = lane&15, row = (lane>>4)*4 + reg
  // acc[am] covers wave rows am*16 (am = mh*4+i -> mh*64 + i*16 = am*16).
  const int colb = n0 + wc * 64 + r16;
  const int rowb = m0 + wr * 128 + cq * 4;

  float wvv[4], ccv[4], pbv[4], obv[4];
#pragma unroll
  for (int ni = 0; ni < 4; ++ni) {
    int n = colb + ni * 16;
    if (EPI == 1) { wvv[ni] = wv[n]; ccv[ni] = cc[n]; pbv[ni] = pb2[n]; }
    else          { obv[ni] = outb[n]; }
  }

#pragma unroll
  for (int am = 0; am < 8; ++am) {
    int mrow = rowb + am * 16;
#pragma unroll
    for (int ni = 0; ni < 4; ++ni) {
      f32x4 v = acc[am][ni];
      int n = colb + ni * 16;
#pragma unroll
      for (int r = 0; r < 4; ++r) {
        int m = mrow + r;
        if (EPI == 1) {
          int h = n >> 8, kq = n & 255;
          float val = wvv[ni] * v[r] + ccv[ni] * cache[((size_t)h * MROW + m) * HID + kq] + pbv[ni];
          outh[(size_t)m * NCOL + n] = f2bf(val);
        } else {
          outf[(size_t)m * NCOL + n] = v[r] + obv[ni];
        }
      }
    }
  }
}

extern "C" void kernel_launch(void* const* d_in, const int* in_sizes, int n_in,
                              void* d_out, int out_size, void* d_ws, size_t ws_size,
                              hipStream_t stream) {
  const float* x      = (const float*)d_in[0];
  const float* proj_w = (const float*)d_in[1];
  const float* proj_b = (const float*)d_in[2];
  const float* mix_w  = (const float*)d_in[3];
  const float* mix_b  = (const float*)d_in[4];
  const float* decay  = (const float*)d_in[5];
  const float* cache  = (const float*)d_in[6];
  const float* out_w  = (const float*)d_in[7];
  const float* out_b  = (const float*)d_in[8];
  const int*   index  = (const int*)d_in[9];

  char* ws = (char*)d_ws;
  ushort* xb  = (ushort*)ws;                         // 64 MiB
  ushort* pwb = (ushort*)(ws + 67108864);            // 32 MiB
  ushort* owb = (ushort*)(ws + 100663296);           // 32 MiB
  ushort* hid = (ushort*)(ws + 134217728);           // 64 MiB
  float*  wv  = (float*)(ws + 201326592);
  float*  cc  = (float*)(ws + 201326592 + 16384);
  float*  pb2 = (float*)(ws + 201326592 + 32768);

  hipFuncSetAttribute((const void*)&gemmkp<1>, hipFuncAttributeMaxDynamicSharedMemorySize, LDS_TOTAL);
  hipFuncSetAttribute((const void*)&gemmkp<0>, hipFuncAttributeMaxDynamicSharedMemorySize, LDS_TOTAL);

  hipLaunchKernelGGL(cvt_f32_bf16, dim3(2048), dim3(256), 0, stream,
                     x, xb, (long)MROW * DIMK / 8);
  hipLaunchKernelGGL(cvt_f32_bf16, dim3(1024), dim3(256), 0, stream,
                     proj_w, pwb, (long)NCOL * DIMK / 8);
  hipLaunchKernelGGL(cvt_f32_bf16, dim3(1024), dim3(256), 0, stream,
                     out_w, owb, (long)NCOL * DIMK / 8);
  hipLaunchKernelGGL(coef_kernel, dim3(16), dim3(256), 0, stream,
                     mix_w, mix_b, decay, proj_b, index, wv, cc, pb2);

  const int grid = (MROW / 256) * (NCOL / 256);   // 512 blocks

  // GEMM1: hidden = mix(x @ proj_w^T) -> bf16
  hipLaunchKernelGGL((gemmkp<1>), dim3(grid), dim3(512), LDS_TOTAL, stream,
                     xb, pwb, nullptr, hid, cache, wv, cc, pb2, nullptr);
  // GEMM2: out = hidden @ out_w^T + out_b -> f32
  hipLaunchKernelGGL((gemmkp<0>), dim3(grid), dim3(512), LDS_TOTAL, stream,
                     hid, owb, (float*)d_out, nullptr, nullptr, nullptr, nullptr, nullptr, out_b);
}

// Round 14
// 586.553 us; speedup vs baseline: 3.2976x; 1.0094x over previous
//
#include <hip/hip_runtime.h>
#include <hip/hip_bf16.h>

// Problem constants
#define MROW 8192   // BATCH
#define DIMK 4096   // DIM (= K of both GEMMs)
#define NCOL 4096   // N_HEADS*HIDDEN = DIM
#define HID  256
#define NH   16
#define SEQL 4096

// GEMM tile geometry: 256x256 tile, BK=32, 16 waves (4M x 4N, wave-tile 64x64),
// ring-of-4 LDS (4 x 32KB = 128KB), one 1024-thread block per CU.
#define BKT 32
#define NKT (DIMK / BKT)       // 128 K-tiles
#define SLOTB 32768            // ring slot: A 16KB + B 16KB
#define LDS_TOTAL (4 * SLOTB)  // 131072
#define NGEMM ((MROW / 256) * (NCOL / 256))   // 512 GEMM blocks
#define NCVT 256                              // piggyback convert blocks (GEMM1)

typedef __attribute__((ext_vector_type(8))) short short8;
typedef __attribute__((ext_vector_type(4))) float f32x4;

__device__ inline ushort f2bf(float f) {
  unsigned u = __float_as_uint(f);
  u += 0x7FFF + ((u >> 16) & 1);   // RNE
  return (ushort)(u >> 16);
}

__device__ inline void gload16(const void* g, void* l) {
  __builtin_amdgcn_global_load_lds(
      (const __attribute__((address_space(1))) void*)g,
      (__attribute__((address_space(3))) void*)l, 16, 0, 0);
}

__device__ inline void cvt8(const float* __restrict__ s, ushort* __restrict__ d, long i) {
  const float4* s4 = (const float4*)(s + i * 8);
  float4 a = s4[0], b = s4[1];
  ushort r[8] = {f2bf(a.x), f2bf(a.y), f2bf(a.z), f2bf(a.w),
                 f2bf(b.x), f2bf(b.y), f2bf(b.z), f2bf(b.w)};
  *(uint4*)(d + i * 8) = *(const uint4*)r;
}

// fused x + proj_w fp32->bf16 convert (one launch)
__global__ void cvt_xpw(const float* __restrict__ x, ushort* __restrict__ xb,
                        const float* __restrict__ pw, ushort* __restrict__ pwb) {
  const long n8x = (long)MROW * DIMK / 8;   // 4194304
  const long n8p = (long)NCOL * DIMK / 8;   // 2097152
  long stride = (long)gridDim.x * blockDim.x;
  for (long i = (long)blockIdx.x * blockDim.x + threadIdx.x; i < n8x + n8p; i += stride) {
    if (i < n8x) cvt8(x, xb, i);
    else         cvt8(pw, pwb, i - n8x);
  }
}

// per-output-column coefficients for the GEMM1 epilogue
__global__ void coef_kernel(const float* __restrict__ mix_w, const float* __restrict__ mix_b,
                            const float* __restrict__ decay_value, const float* __restrict__ proj_b,
                            const int* __restrict__ index_p,
                            float* __restrict__ wv, float* __restrict__ cc, float* __restrict__ pb2) {
  int n = blockIdx.x * blockDim.x + threadIdx.x;   // 0..4095
  if (n >= NCOL) return;
  int h = n >> 8;
  int idx = *index_p;
  float w  = mix_w[h * SEQL + idx];
  float bb = mix_b[h * SEQL + idx];
  float dv = fminf(fmaxf(decay_value[h], 0.9f), 1.0f);
  float decay = powf(dv, 0.125f);                  // 1/DECAY_CONSTANT (=8)
  float coef = (h < NH / 2) ? w * decay : decay;
  wv[n]  = w;
  cc[n]  = coef;
  pb2[n] = w * proj_b[n] + bb;
}

// C = A(MxK)*B^T(NxK), bf16, 16x16x32 MFMA (R6 structure — best measured).
// LDS tile row = 64B, swizzle 16B slot = c ^ ((row>>1)&3) (measured 0 conflicts),
// inverse on the global staging source (linear LDS dest), forward on reads.
// 16 waves, one barrier per K-tile, counted vmcnt across barriers, ring-of-4.
// GEMM1 additionally carries NCVT piggyback blocks (bid >= NGEMM) that convert
// out_w fp32->bf16 under the GEMM's spare memory bandwidth.
template <int EPI>
__global__ __launch_bounds__(1024, 4) void gemm256(
    const ushort* __restrict__ A, const ushort* __restrict__ B,
    float* __restrict__ outf, ushort* __restrict__ outh,
    const float* __restrict__ cache, const float* __restrict__ wv,
    const float* __restrict__ cc, const float* __restrict__ pb2,
    const float* __restrict__ outb,
    const float* __restrict__ owsrc, ushort* __restrict__ owdst) {
  extern __shared__ __align__(16) char smem[];

  const int bid = blockIdx.x;
  if (EPI == 1 && bid >= NGEMM) {
    // ---- piggyback: convert out_w for GEMM2 (rides GEMM1's idle HBM pipe)
    const long n8 = (long)NCOL * DIMK / 8;   // 2097152
    long stride = (long)NCVT * blockDim.x;
    for (long i = (long)(bid - NGEMM) * blockDim.x + threadIdx.x; i < n8; i += stride)
      cvt8(owsrc, owdst, i);
    return;
  }

  const int tid  = threadIdx.x;
  const int lane = tid & 63;
  const int wid  = tid >> 6;      // 0..15
  const int wr = wid >> 2;        // 0..3 (M)
  const int wc = wid & 3;         // 0..3 (N)
  const int r16 = lane & 15;
  const int cq  = lane >> 4;      // 16B column block 0..3

  // XCD swizzle (512 GEMM blocks, bijective)
  const int swz = (bid & 7) * 64 + (bid >> 3);
  const int bm = swz >> 4, bn = swz & 15;   // 32 x 16 tiles
  const int m0 = bm * 256, n0 = bn * 256;

  const ushort* Ag = A + (size_t)m0 * DIMK;
  const ushort* Bg = B + (size_t)n0 * DIMK;

  // ---- precomputed LDS read byte-offsets (loop-invariant; swizzled)
  int aoff[4], boff[4];
#pragma unroll
  for (int i = 0; i < 4; ++i) {
    int arow = wr * 64 + i * 16 + r16;
    aoff[i] = arow * 64 + ((cq ^ ((arow >> 1) & 3)) << 4);
    int brow = wc * 64 + i * 16 + r16;
    boff[i] = 16384 + brow * 64 + ((cq ^ ((brow >> 1) & 3)) << 4);
  }

  // ---- precomputed stage offsets: linear LDS dest, inverse-swizzled global src
  const int soff = tid * 16;                 // [0, 16384)
  const int srow = soff >> 6;
  const int sgo  = srow * DIMK + ((((soff >> 4) & 3) ^ ((srow >> 1) & 3)) << 3);

  f32x4 acc[4][4] = {};

  // prologue: stage K-tiles 0..2 into ring slots 0..2 (2 loads per thread per kt)
#pragma unroll
  for (int kt = 0; kt < 3; ++kt) {
    char* s = smem + kt * SLOTB;
    gload16(Ag + (size_t)sgo + kt * BKT, s + soff);
    gload16(Bg + (size_t)sgo + kt * BKT, s + 16384 + soff);
  }
  asm volatile("s_waitcnt vmcnt(4)" ::: "memory");   // kt0 landed
  __builtin_amdgcn_s_barrier();
  __builtin_amdgcn_sched_barrier(0);

  for (int kt = 0; kt < NKT; ++kt) {
    const char* cur = smem + (kt & 3) * SLOTB;

    short8 af[4], bf[4];
#pragma unroll
    for (int i = 0; i < 4; ++i) bf[i] = *(const short8*)(cur + boff[i]);
#pragma unroll
    for (int i = 0; i < 4; ++i) af[i] = *(const short8*)(cur + aoff[i]);

    // prefetch K-tile kt+3 into ring slot (kt+3)&3 (= (kt-1)&3, consumed last iter)
    if (kt < NKT - 3) {
      char* st = smem + ((kt + 3) & 3) * SLOTB;
      int k0 = (kt + 3) * BKT;
      gload16(Ag + (size_t)sgo + k0, st + soff);
      gload16(Bg + (size_t)sgo + k0, st + 16384 + soff);
    }

    __builtin_amdgcn_s_setprio(1);
#pragma unroll
    for (int mi = 0; mi < 4; ++mi)
#pragma unroll
      for (int ni = 0; ni < 4; ++ni)
        acc[mi][ni] = __builtin_amdgcn_mfma_f32_16x16x32_bf16(af[mi], bf[ni], acc[mi][ni], 0, 0, 0);
    __builtin_amdgcn_s_setprio(0);

    // counted wait: guarantee kt+1 landed; deeper prefetch stays in flight
    // across the barrier (never drains to 0 in steady state).
    if (kt < NKT - 3)       asm volatile("s_waitcnt vmcnt(4)" ::: "memory");
    else if (kt == NKT - 3) asm volatile("s_waitcnt vmcnt(2)" ::: "memory");
    else if (kt == NKT - 2) asm volatile("s_waitcnt vmcnt(0)" ::: "memory");
    __builtin_amdgcn_s_barrier();
    __builtin_amdgcn_sched_barrier(0);
  }

  // ---- epilogue. C/D 16x16 map: col = lane&15, row = (lane>>4)*4 + reg
  const int colb = n0 + wc * 64 + r16;
  const int rowb = m0 + wr * 64 + cq * 4;

  float wvv[4], ccv[4], pbv[4], obv[4];
#pragma unroll
  for (int ni = 0; ni < 4; ++ni) {
    int n = colb + ni * 16;
    if (EPI == 1) { wvv[ni] = wv[n]; ccv[ni] = cc[n]; pbv[ni] = pb2[n]; }
    else          { obv[ni] = outb[n]; }
  }

#pragma unroll
  for (int mi = 0; mi < 4; ++mi) {
#pragma unroll
    for (int ni = 0; ni < 4; ++ni) {
      f32x4 v = acc[mi][ni];
      int n = colb + ni * 16;
#pragma unroll
      for (int r = 0; r < 4; ++r) {
        int m = rowb + mi * 16 + r;
        if (EPI == 1) {
          int h = n >> 8, kq = n & 255;
          float val = wvv[ni] * v[r] + ccv[ni] * cache[((size_t)h * MROW + m) * HID + kq] + pbv[ni];
          outh[(size_t)m * NCOL + n] = f2bf(val);
        } else {
          outf[(size_t)m * NCOL + n] = v[r] + obv[ni];
        }
      }
    }
  }
}

extern "C" void kernel_launch(void* const* d_in, const int* in_sizes, int n_in,
                              void* d_out, int out_size, void* d_ws, size_t ws_size,
                              hipStream_t stream) {
  const float* x      = (const float*)d_in[0];
  const float* proj_w = (const float*)d_in[1];
  const float* proj_b = (const float*)d_in[2];
  const float* mix_w  = (const float*)d_in[3];
  const float* mix_b  = (const float*)d_in[4];
  const float* decay  = (const float*)d_in[5];
  const float* cache  = (const float*)d_in[6];
  const float* out_w  = (const float*)d_in[7];
  const float* out_b  = (const float*)d_in[8];
  const int*   index  = (const int*)d_in[9];

  char* ws = (char*)d_ws;
  ushort* xb  = (ushort*)ws;                         // 64 MiB
  ushort* pwb = (ushort*)(ws + 67108864);            // 32 MiB
  ushort* owb = (ushort*)(ws + 100663296);           // 32 MiB
  ushort* hid = (ushort*)(ws + 134217728);           // 64 MiB
  float*  wv  = (float*)(ws + 201326592);
  float*  cc  = (float*)(ws + 201326592 + 16384);
  float*  pb2 = (float*)(ws + 201326592 + 32768);

  hipFuncSetAttribute((const void*)&gemm256<1>, hipFuncAttributeMaxDynamicSharedMemorySize, LDS_TOTAL);
  hipFuncSetAttribute((const void*)&gemm256<0>, hipFuncAttributeMaxDynamicSharedMemorySize, LDS_TOTAL);

  // fused x + proj_w convert (ow convert rides inside GEMM1)
  hipLaunchKernelGGL(cvt_xpw, dim3(3072), dim3(256), 0, stream, x, xb, proj_w, pwb);
  hipLaunchKernelGGL(coef_kernel, dim3(16), dim3(256), 0, stream,
                     mix_w, mix_b, decay, proj_b, index, wv, cc, pb2);

  // GEMM1 (+ piggyback ow-convert blocks): hidden = mix(x @ proj_w^T) -> bf16
  hipLaunchKernelGGL((gemm256<1>), dim3(NGEMM + NCVT), dim3(1024), LDS_TOTAL, stream,
                     xb, pwb, nullptr, hid, cache, wv, cc, pb2, nullptr, out_w, owb);
  // GEMM2: out = hidden @ out_w^T + out_b -> f32
  hipLaunchKernelGGL((gemm256<0>), dim3(NGEMM), dim3(1024), LDS_TOTAL, stream,
                     hid, owb, (float*)d_out, nullptr, nullptr, nullptr, nullptr, nullptr, out_b,
                     nullptr, nullptr);
}